// Round 2
// baseline (343.333 us; speedup 1.0000x reference)
//
#include <hip/hip_runtime.h>
#include <math.h>

// Problem constants
#define HH 56
#define WW 56
#define NB 32
#define CC 256
#define PIX (HH*WW)            // 3136
#define M_TOT (NB*PIX)         // 100352
#define PADH 58
#define PADW 58
#define AW_STRIDE (NB*PADH*PADW)   // 107648 u64 per channel-word plane
#define SPR (WW/4)             // 14 4-pixel slots per row
#define SLOTS (M_TOT/4)        // 25088

typedef unsigned long long u64;

// ---------------------------------------------------------------------------
// Pack weights: per-co mean (double), unbiased std, sw = 2^round(log2 mean|bw|),
// sign bits (ballot), per-(co,tap) weight popcounts for boundary correction.
// Also zeroes the stat accumulators.
// ---------------------------------------------------------------------------
__global__ __launch_bounds__(256) void pack_weights(
    const float* __restrict__ wt, u64* __restrict__ wbits,
    int* __restrict__ pwg, float* __restrict__ swv,
    long long* __restrict__ sumS, long long* __restrict__ sumSS) {
  int co = blockIdx.x;
  int t  = threadIdx.x;          // = ci
  int lane = t & 63, wid = t >> 6;

  float wv[9];
  const float* wp = wt + ((size_t)co*CC + t)*9;
  double psum = 0.0;
#pragma unroll
  for (int k = 0; k < 9; ++k) { wv[k] = wp[k]; psum += (double)wv[k]; }

  __shared__ double redm[4];
#pragma unroll
  for (int off = 32; off > 0; off >>= 1) psum += __shfl_xor(psum, off);
  if (lane == 0) redm[wid] = psum;
  __syncthreads();
  double mean = (redm[0]+redm[1]+redm[2]+redm[3]) * (1.0/2304.0);

  double pabs = 0.0, psq = 0.0;
#pragma unroll
  for (int k = 0; k < 9; ++k) {
    double d = (double)wv[k] - mean;
    pabs += fabs(d);
    psq  += d*d;
  }
#pragma unroll
  for (int off = 32; off > 0; off >>= 1) {
    pabs += __shfl_xor(pabs, off);
    psq  += __shfl_xor(psq,  off);
  }
  __shared__ double reda[4], redq[4];
  __shared__ int pwred[9][4];
  if (lane == 0) { reda[wid] = pabs; redq[wid] = psq; }
  // Sign bits packed 64/word; wave wid covers ci word wid. Also tap popcounts.
#pragma unroll
  for (int k = 0; k < 9; ++k) {
    u64 m = __ballot(((double)wv[k] - mean) > 0.0);
    if (lane == 0) {
      wbits[(size_t)co*36 + k*4 + wid] = m;
      pwred[k][wid] = __popcll(m);
    }
  }
  __syncthreads();
  if (t < 9)
    pwg[co*9 + t] = pwred[t][0]+pwred[t][1]+pwred[t][2]+pwred[t][3];
  if (t == 0) {
    double sa = reda[0]+reda[1]+reda[2]+reda[3];
    double sq = redq[0]+redq[1]+redq[2]+redq[3];
    double stdv = sqrt(sq / 2303.0);                 // torch unbiased std
    double mabs = (sa * (1.0/2304.0)) / stdv;        // mean|bw|
    swv[co] = (float)exp2(rint(log2(mabs)));         // round half-to-even
    sumS[co]  = 0;
    sumSS[co] = 0;
  }
}

// ---------------------------------------------------------------------------
// Pack activations: sign(x) -> padded bitmap [word][n][h+1][w+1].
// Pad cells are zeroed by a hipMemsetAsync before this kernel.
// ---------------------------------------------------------------------------
__global__ __launch_bounds__(256) void pack_acts(
    const float* __restrict__ x, u64* __restrict__ abits) {
  int word = blockIdx.y;                       // 0..3
  int pi = blockIdx.x*256 + threadIdx.x;       // 0..100351
  int n = pi / PIX, pl = pi % PIX;
  int h = pl / WW, w = pl % WW;
  const float* xp = x + ((size_t)n*CC + (size_t)word*64)*PIX + pl;
  u64 bits = 0ull;
#pragma unroll
  for (int c = 0; c < 64; ++c) {
    float v = xp[(size_t)c*PIX];
    bits |= ((u64)(v > 0.0f)) << c;
  }
  abits[(size_t)word*AW_STRIDE + ((size_t)n*PADH + (h+1))*PADW + (w+1)] = bits;
}

// ---------------------------------------------------------------------------
// Binary conv 3x3 pad 1, XNOR-popcount. Thread: 4 consecutive pixels x 8 co.
// Branchless taps (pad reads are zero words); boundary fixed by subtracting
// per-(co,tap) weight popcounts: s = 256*V - 2*(P_all - C).
// ---------------------------------------------------------------------------
template <bool S16>
__global__ __launch_bounds__(256, 2) void bconv(
    const u64* __restrict__ abits, const u64* __restrict__ wbits,
    const int* __restrict__ pwg,
    short* __restrict__ s16out, float* __restrict__ f32out,
    u64* __restrict__ sumS, u64* __restrict__ sumSS) {
  __shared__ u64 lw[4][8][9];       // [word][t][tap], wave-uniform broadcast reads
  __shared__ int lpw[8][9];
  __shared__ int redS[8][4], redQ[8][4];
  int cog = blockIdx.y;
  for (int i = threadIdx.x; i < 288; i += 256) {
    int wd = i / 72, r = i - wd*72, t = r / 9, tap = r - t*9;
    lw[wd][t][tap] = wbits[(size_t)(cog*8 + t)*36 + tap*4 + wd];
  }
  if (threadIdx.x < 72) {
    int t = threadIdx.x / 9, tap = threadIdx.x - t*9;
    lpw[t][tap] = pwg[(cog*8 + t)*9 + tap];
  }
  __syncthreads();

  int slot = blockIdx.x*256 + threadIdx.x;     // 0..25087
  int n = slot / (HH*SPR);
  int r = slot - n*(HH*SPR);
  int h = r / SPR;
  int w0 = 4*(r - h*SPR);
  // padded cell (ph,pw) = image (ph-1,pw-1); top-left tap cell = padded (h, w0)
  const u64* ab = abits + ((size_t)n*PADH + h)*PADW + w0;

  int P[4][8];
#pragma unroll
  for (int p = 0; p < 4; ++p)
#pragma unroll
    for (int t = 0; t < 8; ++t) P[p][t] = 0;

#pragma unroll 1
  for (int wd = 0; wd < 4; ++wd) {
    const u64* ap = ab + (size_t)wd*AW_STRIDE;
#pragma unroll
    for (int rr = 0; rr < 3; ++rr) {
      u64 A[6];
#pragma unroll
      for (int cc = 0; cc < 6; ++cc) A[cc] = ap[rr*PADW + cc];
#pragma unroll
      for (int t = 0; t < 8; ++t) {
        u64 wv0 = lw[wd][t][rr*3 + 0];   // tap col -1
        u64 wv1 = lw[wd][t][rr*3 + 1];   // tap col  0
        u64 wv2 = lw[wd][t][rr*3 + 2];   // tap col +1
#pragma unroll
        for (int p = 0; p < 4; ++p) {
          P[p][t] += __popcll(A[p] ^ wv0) + __popcll(A[p+1] ^ wv1)
                   + __popcll(A[p+2] ^ wv2);
        }
      }
    }
  }

  // boundary correction: remove pad-tap contributions (popc(0^w) = popc(w))
  int V[4];
#pragma unroll
  for (int p = 0; p < 4; ++p) {
    int wp_ = w0 + p;
    int m = 0x1FF;
    if (h == 0)      m &= ~0x007;
    if (h == HH-1)   m &= ~0x1C0;
    if (wp_ == 0)    m &= ~0x049;
    if (wp_ == WW-1) m &= ~0x124;
    V[p] = __popc(m);
    int inv = 0x1FF ^ m;
    while (inv) {
      int tap = __ffs(inv) - 1; inv &= inv - 1;
#pragma unroll
      for (int t = 0; t < 8; ++t) P[p][t] -= lpw[t][tap];
    }
  }

  int lane = threadIdx.x & 63, wid = threadIdx.x >> 6;
  size_t obase = ((size_t)n*CC + cog*8)*PIX + h*WW + w0;
#pragma unroll
  for (int t = 0; t < 8; ++t) {
    int s0 = 256*V[0] - 2*P[0][t];
    int s1 = 256*V[1] - 2*P[1][t];
    int s2 = 256*V[2] - 2*P[2][t];
    int s3 = 256*V[3] - 2*P[3][t];
    if (S16) {
      int lo = (s0 & 0xFFFF) | (s1 << 16);
      int hi = (s2 & 0xFFFF) | (s3 << 16);
      *(int2*)(s16out + obase + (size_t)t*PIX) = make_int2(lo, hi);
    } else {
      *(float4*)(f32out + obase + (size_t)t*PIX) =
          make_float4((float)s0, (float)s1, (float)s2, (float)s3);
    }
    int ss = s0 + s1 + s2 + s3;
    int qq = s0*s0 + s1*s1 + s2*s2 + s3*s3;   // <= 2.2e7, wave-sum fits int32
#pragma unroll
    for (int off = 32; off > 0; off >>= 1) {
      ss += __shfl_xor(ss, off);
      qq += __shfl_xor(qq, off);
    }
    if (lane == 0) { redS[t][wid] = ss; redQ[t][wid] = qq; }
  }
  __syncthreads();
  if (threadIdx.x < 8) {
    int t = threadIdx.x;
    long long S = (long long)redS[t][0]+redS[t][1]+redS[t][2]+redS[t][3];
    long long Q = (long long)redQ[t][0]+redQ[t][1]+redQ[t][2]+redQ[t][3];
    atomicAdd(&sumS [cog*8 + t], (u64)S);   // 2's-complement wrap ok
    atomicAdd(&sumSS[cog*8 + t], (u64)Q);
  }
}

// ---------------------------------------------------------------------------
// Per-channel BN fold: out = clip(s*A + B)
// ---------------------------------------------------------------------------
__global__ void finalize_stats(
    const long long* __restrict__ sumS, const long long* __restrict__ sumSS,
    const float* __restrict__ swv,
    const float* __restrict__ gamma, const float* __restrict__ beta,
    float* __restrict__ AB) {
  int c = threadIdx.x;
  double mu  = (double)sumS[c]  / (double)M_TOT;
  double var = (double)sumSS[c] / (double)M_TOT - mu*mu;
  double sw  = (double)swv[c];
  double inv = 1.0 / sqrt(sw*sw*var + 1e-5);
  double scale = (double)gamma[c] * sw * inv;
  double shift = (double)beta[c] - scale * mu;
  AB[c]      = (float)scale;
  AB[CC + c] = (float)shift;
}

__global__ __launch_bounds__(256) void bn_apply_s16(
    const short* __restrict__ s, float* __restrict__ out,
    const float* __restrict__ AB, int n8) {
  int i = blockIdx.x*256 + threadIdx.x;
  if (i >= n8) return;
  union { int4 v; short sh[8]; } u;
  u.v = ((const int4*)s)[i];
  int c = ((i*8) / PIX) & (CC-1);   // PIX % 8 == 0 -> c uniform across the 8
  float a = AB[c], b = AB[CC + c];
  float4 o0, o1;
  o0.x = fminf(1.f, fmaxf(-1.f, (float)u.sh[0]*a + b));
  o0.y = fminf(1.f, fmaxf(-1.f, (float)u.sh[1]*a + b));
  o0.z = fminf(1.f, fmaxf(-1.f, (float)u.sh[2]*a + b));
  o0.w = fminf(1.f, fmaxf(-1.f, (float)u.sh[3]*a + b));
  o1.x = fminf(1.f, fmaxf(-1.f, (float)u.sh[4]*a + b));
  o1.y = fminf(1.f, fmaxf(-1.f, (float)u.sh[5]*a + b));
  o1.z = fminf(1.f, fmaxf(-1.f, (float)u.sh[6]*a + b));
  o1.w = fminf(1.f, fmaxf(-1.f, (float)u.sh[7]*a + b));
  ((float4*)out)[2*i]   = o0;
  ((float4*)out)[2*i+1] = o1;
}

__global__ __launch_bounds__(256) void bn_apply_f32(
    float* __restrict__ out, const float* __restrict__ AB, int n4) {
  int i = blockIdx.x*256 + threadIdx.x;
  if (i >= n4) return;
  float4 v = ((float4*)out)[i];
  int c = ((i*4) / PIX) & (CC-1);
  float a = AB[c], b = AB[CC + c];
  v.x = fminf(1.f, fmaxf(-1.f, v.x*a + b));
  v.y = fminf(1.f, fmaxf(-1.f, v.y*a + b));
  v.z = fminf(1.f, fmaxf(-1.f, v.z*a + b));
  v.w = fminf(1.f, fmaxf(-1.f, v.w*a + b));
  ((float4*)out)[i] = v;
}

extern "C" void kernel_launch(void* const* d_in, const int* in_sizes, int n_in,
                              void* d_out, int out_size, void* d_ws, size_t ws_size,
                              hipStream_t stream) {
  (void)in_sizes; (void)n_in; (void)out_size;
  const float* x     = (const float*)d_in[0];
  const float* wt    = (const float*)d_in[1];
  const float* gamma = (const float*)d_in[2];
  const float* beta  = (const float*)d_in[3];
  float* out = (float*)d_out;

  char* ws = (char*)d_ws;
  size_t off = 0;
  u64* abits = (u64*)(ws + off);
  size_t abits_bytes = (size_t)4*AW_STRIDE*8;
  off += abits_bytes;            off = (off + 255) & ~(size_t)255;
  u64* wbits = (u64*)(ws + off); off += (size_t)256*36*8;
  off = (off + 255) & ~(size_t)255;
  int* pwg  = (int*)(ws + off);  off += 256*9*4;
  off = (off + 255) & ~(size_t)255;
  float* swv = (float*)(ws + off); off += 256*4;
  float* AB  = (float*)(ws + off); off += 512*4;
  off = (off + 255) & ~(size_t)255;
  long long* sumS  = (long long*)(ws + off); off += 256*8;
  long long* sumSS = (long long*)(ws + off); off += 256*8;
  off = (off + 255) & ~(size_t)255;
  short* sbuf = (short*)(ws + off);
  bool s16 = (ws_size >= off + (size_t)M_TOT*CC*2);

  hipMemsetAsync(abits, 0, abits_bytes, stream);   // zero pad cells
  pack_weights<<<256, 256, 0, stream>>>(wt, wbits, pwg, swv, sumS, sumSS);
  pack_acts<<<dim3(M_TOT/256, 4), 256, 0, stream>>>(x, abits);
  if (s16) {
    bconv<true><<<dim3(SLOTS/256, CC/8), 256, 0, stream>>>(
        abits, wbits, pwg, sbuf, out, (u64*)sumS, (u64*)sumSS);
  } else {
    bconv<false><<<dim3(SLOTS/256, CC/8), 256, 0, stream>>>(
        abits, wbits, pwg, sbuf, out, (u64*)sumS, (u64*)sumSS);
  }
  finalize_stats<<<1, 256, 0, stream>>>(sumS, sumSS, swv, gamma, beta, AB);
  if (s16) {
    bn_apply_s16<<<(M_TOT*CC/8 + 255)/256, 256, 0, stream>>>(
        sbuf, out, AB, M_TOT*CC/8);
  } else {
    bn_apply_f32<<<(M_TOT*CC/4 + 255)/256, 256, 0, stream>>>(
        out, AB, M_TOT*CC/4);
  }
}

// Round 3
// 317.272 us; speedup vs baseline: 1.0821x; 1.0821x over previous
//
#include <hip/hip_runtime.h>
#include <math.h>

// Problem constants
#define HH 56
#define WW 56
#define NB 32
#define CC 256
#define PIX 3136               // 56*56
#define M_TOT 100352           // 32*3136
#define PADH 58
#define PADW 58
#define ACTQ_BYTES ((size_t)NB*PADH*PADW*CC)   // 27,553,792
#define WQ_BYTES ((size_t)9*CC*CC)             // 589,824
#define SBUF_BYTES ((size_t)M_TOT*CC*2)        // 51,380,224

typedef unsigned int u32;
typedef unsigned long long u64;
typedef int v4i __attribute__((ext_vector_type(4)));

// ---------------------------------------------------------------------------
// Pack weights: per-co mean (double), unbiased std, sw = 2^round(log2 mean|bw|),
// and sign bytes wq[tap][co][ci] in {-1,+1}. Zeroes stat accumulators.
// ---------------------------------------------------------------------------
__global__ __launch_bounds__(256) void pack_weights_i8(
    const float* __restrict__ wt, signed char* __restrict__ wq,
    float* __restrict__ swv,
    long long* __restrict__ sumS, long long* __restrict__ sumSS) {
  int co = blockIdx.x;
  int t  = threadIdx.x;          // = ci
  int lane = t & 63, wid = t >> 6;

  float wv[9];
  const float* wp = wt + ((size_t)co*CC + t)*9;
  double psum = 0.0;
#pragma unroll
  for (int k = 0; k < 9; ++k) { wv[k] = wp[k]; psum += (double)wv[k]; }

  __shared__ double redm[4];
#pragma unroll
  for (int off = 32; off > 0; off >>= 1) psum += __shfl_xor(psum, off);
  if (lane == 0) redm[wid] = psum;
  __syncthreads();
  double mean = (redm[0]+redm[1]+redm[2]+redm[3]) * (1.0/2304.0);

  double pabs = 0.0, psq = 0.0;
#pragma unroll
  for (int k = 0; k < 9; ++k) {
    double d = (double)wv[k] - mean;
    pabs += fabs(d);
    psq  += d*d;
  }
#pragma unroll
  for (int off = 32; off > 0; off >>= 1) {
    pabs += __shfl_xor(pabs, off);
    psq  += __shfl_xor(psq,  off);
  }
  __shared__ double reda[4], redq[4];
  if (lane == 0) { reda[wid] = pabs; redq[wid] = psq; }
  __syncthreads();
  if (t == 0) {
    double sa = reda[0]+reda[1]+reda[2]+reda[3];
    double sq = redq[0]+redq[1]+redq[2]+redq[3];
    double stdv = sqrt(sq / 2303.0);                 // torch unbiased std
    double mabs = (sa * (1.0/2304.0)) / stdv;        // mean|bw|
    swv[co] = (float)exp2(rint(log2(mabs)));         // round half-to-even
    sumS[co]  = 0;
    sumSS[co] = 0;
  }
  // sign bytes: wq[k][co][ci] (B^T layout rows = co, contiguous ci)
#pragma unroll
  for (int k = 0; k < 9; ++k)
    wq[((size_t)k*CC + co)*CC + t] =
        (((double)wv[k] - mean) > 0.0) ? (signed char)1 : (signed char)-1;
}

// ---------------------------------------------------------------------------
// Pack activations: sign(x) -> i8 channel-last padded [n][h+1][w+1][ci].
// Each thread owns (one pixel, 64 ci): reads coalesced along pl, transposes
// in registers (no LDS), stores 4x uint4. Borders pre-zeroed by memset.
// ---------------------------------------------------------------------------
__global__ __launch_bounds__(256) void pack_acts_i8(
    const float* __restrict__ x, signed char* __restrict__ actq) {
  int n = blockIdx.y, tile = blockIdx.x;               // 49 tiles of 64 pl
  int lane = threadIdx.x & 63, cw = threadIdx.x >> 6;  // cw: 64-ci group
  int pl = tile*64 + lane;
  int h = pl / WW, w = pl % WW;
  const float* xp = x + ((size_t)(n*CC + cw*64))*PIX + pl;
  u32 wrd[16];
#pragma unroll
  for (int c16 = 0; c16 < 16; ++c16) {
    u32 v = 0;
#pragma unroll
    for (int b = 0; b < 4; ++b) {
      float f = xp[(size_t)(c16*4 + b)*PIX];
      v |= (f > 0.0f ? 0x01u : 0xFFu) << (8*b);   // +1 / -1 as i8
    }
    wrd[c16] = v;
  }
  signed char* dst = actq + ((size_t)(n*PADH + h+1)*PADW + (w+1))*CC + cw*64;
#pragma unroll
  for (int q = 0; q < 4; ++q)
    ((uint4*)dst)[q] = make_uint4(wrd[4*q], wrd[4*q+1], wrd[4*q+2], wrd[4*q+3]);
}

// ---------------------------------------------------------------------------
// Implicit-GEMM binary conv via mfma_i32_16x16x64_i8.
// M=100352 (n,h,w), N=256 (co), K=9 taps x 256 ci. BM=BN=128, BK=64.
// Per wave: 32 rows x 128 cols = 2x8 frags. LDS rows padded to 96B
// (conflict-free for b128: bank = (24m+4q+j)%32 covers each bank exactly 8x).
// Exact i32; epilogue writes s16 (or f32) + per-channel sum/sumsq atomics.
// ---------------------------------------------------------------------------
template <bool S16>
__global__ __launch_bounds__(256, 3) void bconv_mfma(
    const signed char* __restrict__ actq, const signed char* __restrict__ wq,
    short* __restrict__ s16out, float* __restrict__ f32out,
    u64* __restrict__ sumS, u64* __restrict__ sumSS) {
  __shared__ char lds[24576] __attribute__((aligned(16)));  // A:[0,12288) B:[12288,24576)
  __shared__ int colS[128], colQ[128];

  int t = threadIdx.x;
  int lane = t & 63, wvid = t >> 6;
  int lm = lane & 15, quad = lane >> 4;
  int Mbase = blockIdx.x * 128;
  int n0 = blockIdx.y * 128;

  if (t < 128) { colS[t] = 0; colQ[t] = 0; }

  // staging assignment: rows r0 and r0+64, 16B chunk c16 of the 64B K-slice
  int r0 = t >> 2, c16 = t & 3;
  const signed char* pA0;
  const signed char* pA1;
  {
    int P = Mbase + r0;
    int n_ = P / PIX, pl_ = P % PIX, h_ = pl_ / WW, w_ = pl_ % WW;
    pA0 = actq + ((size_t)(n_*PADH + h_+1)*PADW + (w_+1))*CC + c16*16;
    P += 64;
    n_ = P / PIX; pl_ = P % PIX; h_ = pl_ / WW; w_ = pl_ % WW;
    pA1 = actq + ((size_t)(n_*PADH + h_+1)*PADW + (w_+1))*CC + c16*16;
  }
  const signed char* pB = wq + ((size_t)(n0 + r0))*CC + c16*16;

  int wa = r0*96 + c16*16;                         // LDS write addr (16B aligned)
  int aaddr = (wvid*32 + lm)*96 + quad*16;         // A frag base, +i*1536
  int baddr = 12288 + lm*96 + quad*16;             // B frag base, +j*1536

  v4i acc[2][8];
#pragma unroll
  for (int i = 0; i < 2; ++i)
#pragma unroll
    for (int j = 0; j < 8; ++j) acc[i][j] = 0;

#pragma unroll 1
  for (int tap = 0; tap < 9; ++tap) {
    int dh = tap/3 - 1, dw = tap%3 - 1;
    int aoff = (dh*PADW + dw)*CC;                  // tap shift in padded actq
    size_t boff = (size_t)tap*CC*CC;
#pragma unroll 1
    for (int kq = 0; kq < 4; ++kq) {
      int ko = kq*64;
      uint4 a0 = *(const uint4*)(pA0 + aoff + ko);
      uint4 a1 = *(const uint4*)(pA1 + aoff + ko);
      uint4 b0 = *(const uint4*)(pB + boff + ko);
      uint4 b1 = *(const uint4*)(pB + boff + ko + 64*CC);
      __syncthreads();                             // prior frag reads done
      *(uint4*)(lds + wa)               = a0;
      *(uint4*)(lds + wa + 6144)        = a1;      // +64 rows * 96
      *(uint4*)(lds + 12288 + wa)       = b0;
      *(uint4*)(lds + 12288 + wa + 6144)= b1;
      __syncthreads();
      v4i af0 = *(const v4i*)(lds + aaddr);
      v4i af1 = *(const v4i*)(lds + aaddr + 1536);
      v4i bf[8];
#pragma unroll
      for (int j = 0; j < 8; ++j) bf[j] = *(const v4i*)(lds + baddr + j*1536);
#pragma unroll
      for (int j = 0; j < 8; ++j) {
        acc[0][j] = __builtin_amdgcn_mfma_i32_16x16x64_i8(af0, bf[j], acc[0][j], 0, 0, 0);
        acc[1][j] = __builtin_amdgcn_mfma_i32_16x16x64_i8(af1, bf[j], acc[1][j], 0, 0, 0);
      }
    }
  }

  // Epilogue: store s (int, exact) + per-channel stats.
  int Sj[8], Qj[8];
#pragma unroll
  for (int j = 0; j < 8; ++j) { Sj[j] = 0; Qj[j] = 0; }

#pragma unroll
  for (int i = 0; i < 2; ++i) {
    int R = Mbase + wvid*32 + i*16 + quad*4;       // rows R..R+3 (regs 0..3)
    int n_ = R / PIX, pl_ = R % PIX;               // R..R+3 same n, consecutive pl
#pragma unroll
    for (int j = 0; j < 8; ++j) {
      int col = n0 + j*16 + lm;
      v4i a = acc[i][j];
      size_t idx = ((size_t)n_*CC + col)*PIX + pl_;
      if (S16) {
        int2 pk;
        pk.x = (a.x & 0xFFFF) | (a.y << 16);
        pk.y = (a.z & 0xFFFF) | (a.w << 16);
        *(int2*)(s16out + idx) = pk;
      } else {
        *(float4*)(f32out + idx) =
            make_float4((float)a.x, (float)a.y, (float)a.z, (float)a.w);
      }
      Sj[j] += a.x + a.y + a.z + a.w;
      Qj[j] += a.x*a.x + a.y*a.y + a.z*a.z + a.w*a.w;
    }
  }
#pragma unroll
  for (int j = 0; j < 8; ++j) {
    int S = Sj[j], Q = Qj[j];
    S += __shfl_xor(S, 16); S += __shfl_xor(S, 32);   // sum over quads
    Q += __shfl_xor(Q, 16); Q += __shfl_xor(Q, 32);
    if (quad == 0) {
      atomicAdd(&colS[j*16 + lm], S);
      atomicAdd(&colQ[j*16 + lm], Q);
    }
  }
  __syncthreads();
  if (t < 128) {
    atomicAdd(&sumS[n0 + t], (u64)(long long)colS[t]);   // 2's-comp wrap ok
    atomicAdd(&sumSS[n0 + t], (u64)(long long)colQ[t]);
  }
}

// ---------------------------------------------------------------------------
// Per-channel BN fold: out = clip(s*A + B)
// ---------------------------------------------------------------------------
__global__ void finalize_stats(
    const long long* __restrict__ sumS, const long long* __restrict__ sumSS,
    const float* __restrict__ swv,
    const float* __restrict__ gamma, const float* __restrict__ beta,
    float* __restrict__ AB) {
  int c = threadIdx.x;
  double mu  = (double)sumS[c]  / (double)M_TOT;
  double var = (double)sumSS[c] / (double)M_TOT - mu*mu;
  double sw  = (double)swv[c];
  double inv = 1.0 / sqrt(sw*sw*var + 1e-5);
  double scale = (double)gamma[c] * sw * inv;
  double shift = (double)beta[c] - scale * mu;
  AB[c]      = (float)scale;
  AB[CC + c] = (float)shift;
}

__global__ __launch_bounds__(256) void bn_apply_s16(
    const short* __restrict__ s, float* __restrict__ out,
    const float* __restrict__ AB, int n8) {
  int i = blockIdx.x*256 + threadIdx.x;
  if (i >= n8) return;
  union { int4 v; short sh[8]; } u;
  u.v = ((const int4*)s)[i];
  int c = ((i*8) / PIX) & (CC-1);   // PIX % 8 == 0 -> c uniform across the 8
  float a = AB[c], b = AB[CC + c];
  float4 o0, o1;
  o0.x = fminf(1.f, fmaxf(-1.f, (float)u.sh[0]*a + b));
  o0.y = fminf(1.f, fmaxf(-1.f, (float)u.sh[1]*a + b));
  o0.z = fminf(1.f, fmaxf(-1.f, (float)u.sh[2]*a + b));
  o0.w = fminf(1.f, fmaxf(-1.f, (float)u.sh[3]*a + b));
  o1.x = fminf(1.f, fmaxf(-1.f, (float)u.sh[4]*a + b));
  o1.y = fminf(1.f, fmaxf(-1.f, (float)u.sh[5]*a + b));
  o1.z = fminf(1.f, fmaxf(-1.f, (float)u.sh[6]*a + b));
  o1.w = fminf(1.f, fmaxf(-1.f, (float)u.sh[7]*a + b));
  ((float4*)out)[2*i]   = o0;
  ((float4*)out)[2*i+1] = o1;
}

__global__ __launch_bounds__(256) void bn_apply_f32(
    float* __restrict__ out, const float* __restrict__ AB, int n4) {
  int i = blockIdx.x*256 + threadIdx.x;
  if (i >= n4) return;
  float4 v = ((float4*)out)[i];
  int c = ((i*4) / PIX) & (CC-1);
  float a = AB[c], b = AB[CC + c];
  v.x = fminf(1.f, fmaxf(-1.f, v.x*a + b));
  v.y = fminf(1.f, fmaxf(-1.f, v.y*a + b));
  v.z = fminf(1.f, fmaxf(-1.f, v.z*a + b));
  v.w = fminf(1.f, fmaxf(-1.f, v.w*a + b));
  ((float4*)out)[i] = v;
}

extern "C" void kernel_launch(void* const* d_in, const int* in_sizes, int n_in,
                              void* d_out, int out_size, void* d_ws, size_t ws_size,
                              hipStream_t stream) {
  (void)in_sizes; (void)n_in; (void)out_size;
  const float* x     = (const float*)d_in[0];
  const float* wt    = (const float*)d_in[1];
  const float* gamma = (const float*)d_in[2];
  const float* beta  = (const float*)d_in[3];
  float* out = (float*)d_out;

  char* ws = (char*)d_ws;
  size_t off = 0;
  signed char* actq = (signed char*)(ws + off);
  off += ACTQ_BYTES;             off = (off + 255) & ~(size_t)255;
  signed char* wq = (signed char*)(ws + off);
  off += WQ_BYTES;               off = (off + 255) & ~(size_t)255;
  float* swv = (float*)(ws + off); off += 1024;
  float* AB  = (float*)(ws + off); off += 2048;
  long long* sumS  = (long long*)(ws + off); off += 2048;
  long long* sumSS = (long long*)(ws + off); off += 2048;
  off = (off + 255) & ~(size_t)255;
  short* sbuf = (short*)(ws + off);
  bool s16 = (ws_size >= off + SBUF_BYTES);

  hipMemsetAsync(actq, 0, ACTQ_BYTES, stream);     // zero padded borders
  pack_weights_i8<<<256, 256, 0, stream>>>(wt, wq, swv, sumS, sumSS);
  pack_acts_i8<<<dim3(49, NB), 256, 0, stream>>>(x, actq);
  if (s16) {
    bconv_mfma<true><<<dim3(M_TOT/128, 2), 256, 0, stream>>>(
        actq, wq, sbuf, nullptr, (u64*)sumS, (u64*)sumSS);
  } else {
    bconv_mfma<false><<<dim3(M_TOT/128, 2), 256, 0, stream>>>(
        actq, wq, nullptr, out, (u64*)sumS, (u64*)sumSS);
  }
  finalize_stats<<<1, 256, 0, stream>>>(sumS, sumSS, swv, gamma, beta, AB);
  if (s16) {
    bn_apply_s16<<<(M_TOT*CC/8 + 255)/256, 256, 0, stream>>>(
        sbuf, out, AB, M_TOT*CC/8);
  } else {
    bn_apply_f32<<<(M_TOT*CC/4 + 255)/256, 256, 0, stream>>>(
        out, AB, M_TOT*CC/4);
  }
}